// Round 12
// baseline (57.756 us; speedup 1.0000x reference)
//
#include <hip/hip_runtime.h>
#include <hip/hip_fp16.h>
#include <math.h>

#define N_NODES 50000
#define N_EDGES 800000
#define D_FEAT 64
#define HALF_B 64                                  // bytes per node per half (32 f16)
#define TAB_HALF_B ((size_t)N_NODES * HALF_B)      // 3.2 MB: fits one XCD's 4MB L2
#define XCHUNKS (N_NODES * 8)                      // 400000 x->f16 chunks (8 elems)
#define NRB 3125                                   // row-blocks: 16 rows each
#define ECAP 512                                   // staged edges/block (4KB LDS)

// ---- f16 helpers ----
__device__ __forceinline__ unsigned pack2h(float a, float b) {
    __half2 h = __floats2half2_rn(a, b);
    return *reinterpret_cast<unsigned*>(&h);
}
__device__ __forceinline__ __half2 as_h2(unsigned u) {
    return *reinterpret_cast<__half2*>(&u);
}

// Fast ELU: native v_exp_f32 (abs threshold 0.765 makes expm1 precision moot).
__device__ __forceinline__ float elu_f(float x) {
    return x > 0.f ? x : (__expf(x) - 1.f);
}

// Prep: row_ptr lower-bound + x (f32) -> f16 SPLIT table xh[2][N][32].
__global__ __launch_bounds__(256) void prep_kernel(const int* __restrict__ rows,
                                                   const float* __restrict__ x,
                                                   int* __restrict__ row_ptr,
                                                   unsigned short* __restrict__ xh) {
    const int i = blockIdx.x * blockDim.x + threadIdx.x;
    if (i <= N_NODES) {
        int lo = 0, hi = N_EDGES;
        while (lo < hi) {
            int mid = (lo + hi) >> 1;
            if (rows[mid] < i) lo = mid + 1; else hi = mid;
        }
        row_ptr[i] = lo;
    }
    if (i < XCHUNKS) {
        const int node = i >> 3;
        const int c8   = i & 7;            // which 8-feature chunk
        const int h    = c8 >> 2;          // features 0-31 -> half 0, 32-63 -> half 1
        const float4 f0 = *reinterpret_cast<const float4*>(x + (size_t)i * 8);
        const float4 f1 = *reinterpret_cast<const float4*>(x + (size_t)i * 8 + 4);
        uint4 w;
        w.x = pack2h(f0.x, f0.y);
        w.y = pack2h(f0.z, f0.w);
        w.z = pack2h(f1.x, f1.y);
        w.w = pack2h(f1.z, f1.w);
        char* dst = (char*)xh + (size_t)h * TAB_HALF_B + (size_t)node * HALF_B + (c8 & 3) * 16;
        *reinterpret_cast<uint4*>(dst) = w;
    }
}

// One 8-edge step; edges from LDS, gathers are 4B/lane (2 f16 features).
template <bool MASKED>
__device__ __forceinline__ void edge_step8(const char* __restrict__ hb,
                                           const int2* __restrict__ elds,
                                           int le, int le1, int boff,
                                           __half2& A, __half2& B) {
    int off[8]; unsigned v2[8];
    #pragma unroll
    for (int k = 0; k < 8; ++k) {
        const int t = le + k;
        const int idx = MASKED ? (t < le1 ? t : le1 - 1) : t;
        const int2 p = elds[idx];
        off[k] = p.x;
        v2[k]  = (unsigned)p.y;
        if (MASKED) v2[k] = (t < le1) ? v2[k] : 0u;
    }
    unsigned gg[8];
    #pragma unroll
    for (int k = 0; k < 8; ++k)
        gg[k] = *reinterpret_cast<const unsigned*>(hb + (unsigned)(off[k] + boff));
    #pragma unroll
    for (int k = 0; k < 8; ++k) {
        const __half2 vv = as_h2(v2[k]);
        if (k & 1) B = __hfma2(vv, as_h2(gg[k]), B);
        else       A = __hfma2(vv, as_h2(gg[k]), A);
    }
}

// SpMM over one FEATURE HALF: grid 2*NRB; half = blockIdx&1 (round-robin XCD
// dispatch => even XCDs only touch half-table 0, odd only half-table 1; each
// 3.2MB half fits a 4MB XCD L2). 16 rows/block, 16 lanes/row, 2 f16 feats/lane.
__global__ __launch_bounds__(256) void gcn_spmm_half(
    const unsigned short* __restrict__ h_in,   // split [2][N][32] f16
    const int*   __restrict__ cols,
    const float* __restrict__ vals,
    const int*   __restrict__ row_ptr,
    const float* __restrict__ scalar_p,
    unsigned short* __restrict__ h_out)        // split [2][N][32] f16
{
    __shared__ int2 elds[ECAP];

    const int tid  = threadIdx.x;
    const int lane = tid & 63;
    const int wave = tid >> 6;
    const int g    = lane >> 4;          // row-group 0..3
    const int f4   = lane & 15;          // 4B feature chunk index
    const int boff = f4 * 4;

    const int half = blockIdx.x & 1;
    const int rb   = (blockIdx.x >> 1) * 16;
    const char* hb = (const char*)h_in + (size_t)half * TAB_HALF_B;

    // Stage this row-block's contiguous edge range: (col*64, half2{v,v}).
    const int eb0 = row_ptr[rb];
    const int eb1 = row_ptr[rb + 16];
    const int cnt = min(eb1 - eb0, ECAP);
    for (int i = tid; i < cnt; i += 256) {
        const int   c = cols[eb0 + i];
        const float v = vals[eb0 + i];
        elds[i] = make_int2(c << 6, (int)pack2h(v, v));
    }
    __syncthreads();

    const int row = rb + wave * 4 + g;
    const float s  = scalar_p[0];
    const int  e0  = row_ptr[row];
    const int  e1  = row_ptr[row + 1];

    __half2 A = __floats2half2_rn(0.f, 0.f);
    __half2 B = A;

    const int ecap = eb0 + cnt;
    const int le0 = e0 - eb0;
    const int le1 = (e1 < ecap ? e1 : ecap) - eb0;
    int le = le0;
    for (; le + 8 <= le1; le += 8)
        edge_step8<false>(hb, elds, le, le1, boff, A, B);
    if (le < le1)
        edge_step8<true>(hb, elds, le, le1, boff, A, B);
    // Overflow beyond staged capacity (essentially never): scalar global path.
    for (int e = (e0 > ecap ? e0 : ecap); e < e1; ++e) {
        const int   c = cols[e];
        const float v = vals[e];
        const unsigned gg = *reinterpret_cast<const unsigned*>(hb + (unsigned)((c << 6) + boff));
        A = __hfma2(as_h2(pack2h(v, v)), as_h2(gg), A);
    }

    const float2 a = __half22float2(A);
    const float2 bb = __half22float2(B);
    const float rx = elu_f((a.x + bb.x) * s);
    const float ry = elu_f((a.y + bb.y) * s);

    char* dst = (char*)h_out + (size_t)half * TAB_HALF_B + (size_t)row * HALF_B + boff;
    *reinterpret_cast<unsigned*>(dst) = pack2h(rx, ry);
}

// Projection: out[row][j] = b[j] + sum_d y[row][d] * W[j][d].
// y in split f16 layout; W staged as f16 pairs (stride-33: conflict-free).
__global__ __launch_bounds__(256) void proj_kernel(
    const unsigned short* __restrict__ y,   // split [2][N][32] f16
    const float* __restrict__ W,            // [64][64] f32
    const float* __restrict__ bvec,         // [64]
    float*       __restrict__ out)          // [N][64] f32
{
    __shared__ unsigned Wh[64 * 33];        // 8.4 KB
    __shared__ float    ylds[4 * 4 * 68];   // 4.3 KB [wave][row][68 pad]

    const int tid  = threadIdx.x;
    const int lane = tid & 63;
    const int wave = tid >> 6;
    const int g    = lane >> 4;
    const int f4   = lane & 15;

    for (int i = tid; i < 64 * 32; i += 256) {
        const int j = i >> 5, c = i & 31;
        Wh[j * 33 + c] = pack2h(W[j * 64 + 2 * c], W[j * 64 + 2 * c + 1]);
    }

    const int rb  = blockIdx.x * 16;
    const int row = rb + wave * 4 + g;
    // Lane f4 covers features 4*f4..4*f4+3: f4<8 from half 0, f4>=8 from half 1.
    const char* src = (const char*)y + (f4 < 8 ? (size_t)0 : TAB_HALF_B)
                    + (size_t)row * HALF_B + (f4 & 7) * 8;
    const uint2 yy = *reinterpret_cast<const uint2*>(src);
    const float2 p0 = __half22float2(as_h2(yy.x));
    const float2 p1 = __half22float2(as_h2(yy.y));
    float* yw = ylds + wave * (4 * 68);
    *reinterpret_cast<float4*>(yw + g * 68 + f4 * 4) = make_float4(p0.x, p0.y, p1.x, p1.y);
    __syncthreads();   // covers Wh and ylds

    const int j = lane;
    const float bj = bvec[j];
    float o0 = bj, o1 = bj, o2 = bj, o3 = bj;
    #pragma unroll
    for (int d0 = 0; d0 < 16; ++d0) {
        const float2 wA = __half22float2(as_h2(Wh[j * 33 + 2 * d0]));
        const float2 wB = __half22float2(as_h2(Wh[j * 33 + 2 * d0 + 1]));
        const float4 y0 = *reinterpret_cast<const float4*>(yw + 0 * 68 + d0 * 4);
        const float4 y1 = *reinterpret_cast<const float4*>(yw + 1 * 68 + d0 * 4);
        const float4 y2 = *reinterpret_cast<const float4*>(yw + 2 * 68 + d0 * 4);
        const float4 y3 = *reinterpret_cast<const float4*>(yw + 3 * 68 + d0 * 4);
        o0 = fmaf(y0.x, wA.x, o0); o0 = fmaf(y0.y, wA.y, o0);
        o0 = fmaf(y0.z, wB.x, o0); o0 = fmaf(y0.w, wB.y, o0);
        o1 = fmaf(y1.x, wA.x, o1); o1 = fmaf(y1.y, wA.y, o1);
        o1 = fmaf(y1.z, wB.x, o1); o1 = fmaf(y1.w, wB.y, o1);
        o2 = fmaf(y2.x, wA.x, o2); o2 = fmaf(y2.y, wA.y, o2);
        o2 = fmaf(y2.z, wB.x, o2); o2 = fmaf(y2.w, wB.y, o2);
        o3 = fmaf(y3.x, wA.x, o3); o3 = fmaf(y3.y, wA.y, o3);
        o3 = fmaf(y3.z, wB.x, o3); o3 = fmaf(y3.w, wB.y, o3);
    }
    const size_t rbase = (size_t)(rb + wave * 4) * D_FEAT;
    out[rbase + 0 * D_FEAT + j] = o0;
    out[rbase + 1 * D_FEAT + j] = o1;
    out[rbase + 2 * D_FEAT + j] = o2;
    out[rbase + 3 * D_FEAT + j] = o3;
}

extern "C" void kernel_launch(void* const* d_in, const int* in_sizes, int n_in,
                              void* d_out, int out_size, void* d_ws, size_t ws_size,
                              hipStream_t stream) {
    const float* x       = (const float*)d_in[0];
    const int*   rows    = (const int*)  d_in[1];
    const int*   cols    = (const int*)  d_in[2];
    const float* vals    = (const float*)d_in[3];
    const float* scalars = (const float*)d_in[4];
    const float* W       = (const float*)d_in[5];
    const float* b       = (const float*)d_in[6];
    float* out = (float*)d_out;

    // ws layout: row_ptr | xh split | h1 split | y split  (~19.4 MB)
    const size_t rp_b = (sizeof(int) * (N_NODES + 1) + 255) & ~size_t(255);
    const size_t tb_b = (2 * TAB_HALF_B + 255) & ~size_t(255);

    int*            row_ptr = (int*)d_ws;
    unsigned short* xh      = (unsigned short*)((char*)d_ws + rp_b);
    unsigned short* h1      = (unsigned short*)((char*)d_ws + rp_b + tb_b);
    unsigned short* yv      = (unsigned short*)((char*)d_ws + rp_b + 2 * tb_b);

    prep_kernel<<<(XCHUNKS + 255) / 256, 256, 0, stream>>>(rows, x, row_ptr, xh);

    gcn_spmm_half<<<2 * NRB, 256, 0, stream>>>(xh, cols, vals, row_ptr, scalars + 0, h1);
    gcn_spmm_half<<<2 * NRB, 256, 0, stream>>>(h1, cols, vals, row_ptr, scalars + 1, yv);

    proj_kernel<<<NRB, 256, 0, stream>>>(yv, W, b, out);
}